// Round 8
// baseline (216.521 us; speedup 1.0000x reference)
//
#include <hip/hip_runtime.h>
#include <hip/hip_bf16.h>
#include <math.h>

// Problem constants
#define BB 32
#define TT 2048
#define DD 64
#define NCHUNK 4
#define TCH (TT / NCHUNK)           // t-range per wave (512)
#define LOG2E 1.4426950408889634f
#define C2    0.7213475204444817f   // log2(e)/2
#define LN2   0.6931471805599453f

typedef __attribute__((ext_vector_type(8))) _Float16 h16x8;  // 8 f16 (4 VGPRs)
typedef __attribute__((ext_vector_type(4))) float    f32x4;  // MFMA C/D frag
typedef __attribute__((ext_vector_type(2))) float    f32x2;  // packed-math pair

// ws layout (bytes)
#define OFF_M    0u                          // float[32*64]          = 8 KB
#define OFF_TICN 8192u                       // float[32*2048]        = 256 KB
#define OFF_HI   270336u                     // f16[32*2048*64]       = 8 MB
#define OFF_LO   8658944u                    // f16[32*2048*64]       = 8 MB
#define OFF_PART 17047552u                   // float2[NCHUNK*65536]  = 2 MB
// total ~19.1 MB

__device__ __forceinline__ float h2f(unsigned short u) {
    _Float16 h; __builtin_memcpy(&h, &u, 2); return (float)h;
}
__device__ __forceinline__ unsigned short f2h(float f) {
    _Float16 h = (_Float16)f; unsigned short u; __builtin_memcpy(&u, &h, 2); return u;
}
__device__ __forceinline__ float fexp2(float x) {
    float r; asm("v_exp_f32 %0, %1" : "=v"(r) : "v"(x)); return r;
}
__device__ __forceinline__ float flog2(float x) {
    float r; asm("v_log_f32 %0, %1" : "=v"(r) : "v"(x)); return r;
}

// ---------- kernel 1: fused L2-normalize -> f16 hi/lo split + M[b,d] sum ----------
__global__ void k_prep(const float* __restrict__ emb,
                       unsigned short* __restrict__ hi, unsigned short* __restrict__ lo,
                       float* __restrict__ M) {
    const int b    = blockIdx.x >> 4;
    const int R0   = (blockIdx.x & 15) * 128;
    const int w    = threadIdx.x >> 6;
    const int l    = threadIdx.x & 63;
    const int sub  = l >> 4;
    const int d4   = l & 15;

    float macc[4] = {0.f, 0.f, 0.f, 0.f};

    #pragma unroll
    for (int it = 0; it < 8; ++it) {
        int row = R0 + w * 32 + it * 4 + sub;
        size_t base = ((size_t)(b * TT + row)) * DD + d4 * 4;
        float4 v = *(const float4*)(emb + base);
        float ss = v.x * v.x + v.y * v.y + v.z * v.z + v.w * v.w;
        #pragma unroll
        for (int off = 1; off < 16; off <<= 1) ss += __shfl_xor(ss, off);
        float inv = 1.0f / fmaxf(sqrtf(ss), 1e-8f);
        float n0 = v.x * inv, n1 = v.y * inv, n2 = v.z * inv, n3 = v.w * inv;
        ushort4 hv, lv;
        hv.x = f2h(n0); lv.x = f2h(n0 - h2f(hv.x));
        hv.y = f2h(n1); lv.y = f2h(n1 - h2f(hv.y));
        hv.z = f2h(n2); lv.z = f2h(n2 - h2f(hv.z));
        hv.w = f2h(n3); lv.w = f2h(n3 - h2f(hv.w));
        *(ushort4*)(hi + base) = hv;
        *(ushort4*)(lo + base) = lv;
        macc[0] += n0; macc[1] += n1; macc[2] += n2; macc[3] += n3;
    }
    #pragma unroll
    for (int j = 0; j < 4; ++j) {
        macc[j] += __shfl_xor(macc[j], 16);
        macc[j] += __shfl_xor(macc[j], 32);
    }
    if (l < 16) {
        #pragma unroll
        for (int j = 0; j < 4; ++j)
            atomicAdd(&M[b * DD + d4 * 4 + j], macc[j]);
    }
}

// ---------- kernel 2: tic max-normalize ----------
__global__ void k_tic(const float* __restrict__ tic, float* __restrict__ ticn) {
    int b = blockIdx.x;
    const float* row = tic + b * TT;
    float m = -1e30f;
    for (int t = threadIdx.x; t < TT; t += 256) m = fmaxf(m, row[t]);
    #pragma unroll
    for (int off = 32; off; off >>= 1) m = fmaxf(m, __shfl_xor(m, off));
    __shared__ float red[4];
    if ((threadIdx.x & 63) == 0) red[threadIdx.x >> 6] = m;
    __syncthreads();
    float mm = fmaxf(fmaxf(red[0], red[1]), fmaxf(red[2], red[3]));
    float inv = 1.0f / mm;
    for (int t = threadIdx.x; t < TT; t += 256) ticn[b * TT + t] = row[t] * inv;
}

// ---------- kernel 3: barrier-free MFMA GEMM + packed KL epilogue ----------
// grid ((TT/64)*NCHUNK, BB), 256 thr = 4 independent waves.
// Wave: 16 p-rows x TCH targets, everything in registers, B-frags direct from
// global (64 lanes = 16 rows x 4 chunks = 2KB contiguous -> fully coalesced,
// reuse served by L1/L2). Zero LDS in the hot loop, zero barriers.
__launch_bounds__(256)
__global__ void k_main(const unsigned short* __restrict__ hi,
                       const unsigned short* __restrict__ lo,
                       const float* __restrict__ ticn,
                       const float* __restrict__ M,
                       float2* __restrict__ part) {
    const int b     = blockIdx.y;
    const int px    = blockIdx.x >> 2;          // NCHUNK=4
    const int chunk = blockIdx.x & 3;
    const int w     = threadIdx.x >> 6;
    const int l     = threadIdx.x & 63;
    const int lr    = l & 15;                   // A/B row within fragment
    const int lg    = l >> 4;                   // k-group (A/B), row-group (C)
    const int p0    = px * 64 + w * 16;
    const int tbase = chunk * TCH;

    // --- persistent A fragments: row p0+lr, k = ks*32 + lg*8 ---
    h16x8 Ah[2], Al[2];
    #pragma unroll
    for (int ks = 0; ks < 2; ++ks) {
        size_t off = ((size_t)(b * TT + p0 + lr)) * DD + ks * 32 + lg * 8;
        Ah[ks] = *(const h16x8*)(hi + off);
        Al[ks] = *(const h16x8*)(lo + off);
    }

    // --- sinv: dot(ne_row, M) from A-frags (row lr) ---
    const float* Mb = M + b * DD;
    float mv[16];
    *(float4*)&mv[0]  = *(const float4*)(Mb + lg * 8);
    *(float4*)&mv[4]  = *(const float4*)(Mb + lg * 8 + 4);
    *(float4*)&mv[8]  = *(const float4*)(Mb + 32 + lg * 8);
    *(float4*)&mv[12] = *(const float4*)(Mb + 32 + lg * 8 + 4);
    float dot = 0.f;
    #pragma unroll
    for (int ks = 0; ks < 2; ++ks)
        #pragma unroll
        for (int e = 0; e < 8; ++e) {
            float av = (float)Ah[ks][e] + (float)Al[ks][e];
            dot = fmaf(av, mv[ks * 8 + e], dot);
        }
    dot += __shfl_xor(dot, 16);
    dot += __shfl_xor(dot, 32);                 // lane holds full dot of row lr

    float tpl = ticn[b * TT + p0 + lr];         // tic of row lr

    // --- per-row-pair packed constants; C rows this lane owns: lg*4 + {0..3} ---
    f32x2 a2[2], b2[2], si2[2], sip2[2], SP2[2], KA2[2];
    #pragma unroll
    for (int pr = 0; pr < 2; ++pr) {
        #pragma unroll
        for (int j = 0; j < 2; ++j) {
            int rsel  = lg * 4 + pr * 2 + j;
            float dv  = __shfl(dot, rsel);
            float tp  = __shfl(tpl, rsel);
            float si  = 1.0f / (dv + (float)TT);
            a2[pr][j]   = -C2 * tp * tp;
            b2[pr][j]   = LOG2E * tp;
            si2[pr][j]  = si;
            sip2[pr][j] = si + 1e-6f;
            SP2[pr][j]  = 0.f;
            KA2[pr][j]  = 0.f;
        }
    }

    // --- t-loop: 8 tiles of 64 targets, no barriers ---
    for (int tile = 0; tile < TCH / 64; ++tile) {
        const int t0 = tbase + tile * 64;
        const unsigned short* hb = hi + ((size_t)(b * TT + t0)) * DD;

        // B fragments direct from global: col = ni*16+lr, k = ks*32+lg*8
        h16x8 Fh[4][2];
        #pragma unroll
        for (int ni = 0; ni < 4; ++ni)
            #pragma unroll
            for (int ks = 0; ks < 2; ++ks)
                Fh[ni][ks] = *(const h16x8*)(hb + (ni * 16 + lr) * DD + ks * 32 + lg * 8);

        float tt[4], qq[4];
        #pragma unroll
        for (int ni = 0; ni < 4; ++ni) {
            tt[ni] = ticn[b * TT + t0 + ni * 16 + lr];
            qq[ni] = (-C2 * tt[ni]) * tt[ni];
        }

        // MFMA: acc = hi_a.hi_b + lo_a.hi_b
        f32x4 acc[4];
        #pragma unroll
        for (int ni = 0; ni < 4; ++ni) {
            f32x4 a = {0.f, 0.f, 0.f, 0.f};
            a = __builtin_amdgcn_mfma_f32_16x16x32_f16(Ah[0], Fh[ni][0], a, 0, 0, 0);
            a = __builtin_amdgcn_mfma_f32_16x16x32_f16(Ah[1], Fh[ni][1], a, 0, 0, 0);
            a = __builtin_amdgcn_mfma_f32_16x16x32_f16(Al[0], Fh[ni][0], a, 0, 0, 0);
            a = __builtin_amdgcn_mfma_f32_16x16x32_f16(Al[1], Fh[ni][1], a, 0, 0, 0);
            acc[ni] = a;
        }

        // packed epilogue: pairs of C-rows per v_pk_* op
        #pragma unroll
        for (int ni = 0; ni < 4; ++ni) {
            f32x2 tt2 = {tt[ni], tt[ni]};
            f32x2 qq2 = {qq[ni], qq[ni]};
            #pragma unroll
            for (int pr = 0; pr < 2; ++pr) {
                f32x2 acc2 = {acc[ni][2 * pr], acc[ni][2 * pr + 1]};
                f32x2 arg  = b2[pr] * tt2 + a2[pr];      // v_pk_fma
                arg        = arg + qq2;                  // v_pk_add
                f32x2 e    = {fexp2(arg[0]), fexp2(arg[1])};
                f32x2 x    = acc2 * si2[pr] + sip2[pr];  // v_pk_fma
                f32x2 l2v  = {flog2(x[0]), flog2(x[1])};
                f32x2 d    = arg - l2v;                  // v_pk_add(-)
                KA2[pr]    = e * d + KA2[pr];            // v_pk_fma
                SP2[pr]    = SP2[pr] + e;                // v_pk_add
            }
        }
    }

    // --- reduce over 16 col-lanes within each lg group ---
    #pragma unroll
    for (int pr = 0; pr < 2; ++pr) {
        #pragma unroll
        for (int off = 1; off < 16; off <<= 1) {
            SP2[pr][0] += __shfl_xor(SP2[pr][0], off);
            SP2[pr][1] += __shfl_xor(SP2[pr][1], off);
            KA2[pr][0] += __shfl_xor(KA2[pr][0], off);
            KA2[pr][1] += __shfl_xor(KA2[pr][1], off);
        }
    }
    if (lr == 0) {   // lanes 0,16,32,48 hold rows lg*4 + {0..3}
        #pragma unroll
        for (int pr = 0; pr < 2; ++pr)
            #pragma unroll
            for (int j = 0; j < 2; ++j) {
                int p = p0 + lg * 4 + pr * 2 + j;
                part[(size_t)chunk * (BB * TT) + b * TT + p] =
                    make_float2(SP2[pr][j], KA2[pr][j]);
            }
    }
}

// ---------- kernel 4: combine partials, nonlinear reduce ----------
__global__ void k_fin(const float2* __restrict__ part, float* __restrict__ out) {
    int g = blockIdx.x * 256 + threadIdx.x;   // b*TT + p
    float SP = 0.f, KA2 = 0.f;
    #pragma unroll
    for (int c = 0; c < NCHUNK; ++c) {
        float2 q = part[(size_t)c * (BB * TT) + g];
        SP += q.x; KA2 += q.y;
    }
    float R = LN2 * (KA2 / SP) - __logf(SP);
    #pragma unroll
    for (int off = 32; off; off >>= 1) R += __shfl_xor(R, off);
    __shared__ float rb[4];
    if ((threadIdx.x & 63) == 0) rb[threadIdx.x >> 6] = R;
    __syncthreads();
    if (threadIdx.x == 0)
        atomicAdd(out, (rb[0] + rb[1] + rb[2] + rb[3]) * (1.0f / 65536.0f));
}

extern "C" void kernel_launch(void* const* d_in, const int* in_sizes, int n_in,
                              void* d_out, int out_size, void* d_ws, size_t ws_size,
                              hipStream_t stream) {
    const float* emb = (const float*)d_in[0];  // [B, T, D] fp32
    const float* tic = (const float*)d_in[1];  // [B, T] fp32
    float* out = (float*)d_out;
    char*  ws  = (char*)d_ws;

    float*          M    = (float*)(ws + OFF_M);
    float*          ticn = (float*)(ws + OFF_TICN);
    unsigned short* hi   = (unsigned short*)(ws + OFF_HI);
    unsigned short* lo   = (unsigned short*)(ws + OFF_LO);
    float2*         part = (float2*)(ws + OFF_PART);

    hipMemsetAsync(out, 0, sizeof(float), stream);
    hipMemsetAsync(M, 0, BB * DD * sizeof(float), stream);

    k_prep<<<BB * 16, 256, 0, stream>>>(emb, hi, lo, M);
    k_tic <<<BB, 256, 0, stream>>>(tic, ticn);
    k_main<<<dim3((TT / 64) * NCHUNK, BB), 256, 0, stream>>>(hi, lo, ticn, M, part);
    k_fin <<<(BB * TT) / 256, 256, 0, stream>>>(part, out);
}